// Round 4
// baseline (193.913 us; speedup 1.0000x reference)
//
#include <hip/hip_runtime.h>
#include <stdint.h>

#define B_ 128
#define N_ 512
#define I_ 256
#define M_ 32
#define D_ 16
#define NT 8            // K-tiles of 32 (I_/32)

typedef __attribute__((ext_vector_type(4))) float f32x4;
typedef __attribute__((ext_vector_type(4))) float float4v;
typedef __attribute__((ext_vector_type(8))) short short8;     // 8 bf16 MFMA frag
typedef __attribute__((ext_vector_type(4))) unsigned int u32x4;

__device__ __forceinline__ float bf2f(unsigned short u) {
    union { unsigned int i; float f; } v; v.i = ((unsigned int)u) << 16; return v.f;
}
__device__ __forceinline__ unsigned short f2bf(float f) {
    union { float f; unsigned int i; } v; v.f = f;
    unsigned int r = v.i + 0x7FFFu + ((v.i >> 16) & 1u);   // RNE
    return (unsigned short)(r >> 16);
}

__device__ __forceinline__ void gload16(const void* g, void* l) {
    __builtin_amdgcn_global_load_lds(
        (const __attribute__((address_space(1))) void*)g,
        (__attribute__((address_space(3))) void*)l, 16, 0, 0);
}

// Read one bf16 MFMA fragment (8 consecutive k) from swizzled fp32 LDS tile.
// Row stride 32 floats (128 B); granule g (16 B) of row r stored at g ^ (r&7).
__device__ __forceinline__ short8 ldfrag(const float* buf, int row, int g0) {
    const int r7 = row & 7;
    const f32x4* rp = (const f32x4*)(buf + row * 32);
    f32x4 lo = rp[g0 ^ r7];
    f32x4 hi = rp[(g0 + 1) ^ r7];
    unsigned int u0, u1, u2, u3;
    asm("v_cvt_pk_bf16_f32 %0, %1, %2" : "=v"(u0) : "v"(lo[0]), "v"(lo[1]));
    asm("v_cvt_pk_bf16_f32 %0, %1, %2" : "=v"(u1) : "v"(lo[2]), "v"(lo[3]));
    asm("v_cvt_pk_bf16_f32 %0, %1, %2" : "=v"(u2) : "v"(hi[0]), "v"(hi[1]));
    asm("v_cvt_pk_bf16_f32 %0, %1, %2" : "=v"(u3) : "v"(hi[2]), "v"(hi[3]));
    u32x4 uv = {u0, u1, u2, u3};
    return __builtin_bit_cast(short8, uv);
}

// -----------------------------------------------------------------------------
// Kernel 1: inputs_hat[b,m,n,d] = sum_i x[b,n,i] * W[m,n,d,i]
// Per block: one n, 8 m's (128 cols), 128 b-rows. BK=32 fp32 staged via
// global_load_lds (pre-swizzled per-lane source, linear LDS dest), double-
// buffered, counted vmcnt(8), raw s_barrier (no vmcnt(0) drain in loop).
// bf16 conversion at fragment read (v_cvt_pk_bf16_f32, RNE).
// -----------------------------------------------------------------------------
__global__ __launch_bounds__(256) void hat_gemm(const float* __restrict__ x,
                                                const float* __restrict__ W,
                                                unsigned short* __restrict__ hat) {
    __shared__ float As[2][128 * 32];   // [buf][row*32 + k], 16 KB each
    __shared__ float Bs[2][128 * 32];

    const int n    = blockIdx.y;
    const int mc   = blockIdx.x;        // m in [mc*8, mc*8+8)
    const int tid  = threadIdx.x;
    const int lane = tid & 63;
    const int w    = tid >> 6;          // wave 0..3 -> rows [w*32, w*32+32)

    const int lrow8 = lane >> 3;        // row within 8-row group (== row&7)
    const int lg    = lane & 7;         // dest granule
    const int gsrc  = lg ^ lrow8;       // pre-swizzled source granule

    // A source base: row (b) = w*32 + i*8 + lrow8
    const float* xs = x + ((size_t)(w * 32 + lrow8) * N_ + n) * I_ + gsrc * 4;

    f32x4 acc[2][8];
    #pragma unroll
    for (int a = 0; a < 2; ++a)
        #pragma unroll
        for (int c = 0; c < 8; ++c) { f32x4 z = {0.f, 0.f, 0.f, 0.f}; acc[a][c] = z; }

    // stage wave-w's 32 A-rows and 32 B-rows of k-tile kt into buffer bb
    auto stage = [&](int kt, int bb) {
        #pragma unroll
        for (int i = 0; i < 4; ++i) {
            gload16(xs + (size_t)i * 8 * N_ * I_ + kt * 32,
                    &As[bb][(w * 32 + i * 8) * 32]);
        }
        #pragma unroll
        for (int i = 0; i < 4; ++i) {
            const int rB = w * 32 + i * 8 + lrow8;      // col = m_local*16 + d
            const int m  = mc * 8 + (rB >> 4);
            const int d  = rB & 15;
            const float* wsrc = W + (((size_t)m * N_ + n) * D_ + d) * I_ + kt * 32 + gsrc * 4;
            gload16(wsrc, &Bs[bb][(w * 32 + i * 8) * 32]);
        }
    };

    stage(0, 0);   // prologue

    for (int kt = 0; kt < NT; ++kt) {
        if (kt + 1 < NT) {
            stage(kt + 1, (kt + 1) & 1);
            asm volatile("s_waitcnt vmcnt(8)" ::: "memory");   // tile kt landed
        } else {
            asm volatile("s_waitcnt vmcnt(0)" ::: "memory");
        }
        __builtin_amdgcn_sched_barrier(0);
        __builtin_amdgcn_s_barrier();          // all waves' kt data visible
        __builtin_amdgcn_sched_barrier(0);

        const float* Ab = &As[kt & 1][0];
        const float* Bb = &Bs[kt & 1][0];
        const int g0 = (lane >> 4) * 2;        // frag k-granules g0, g0+1

        short8 a0 = ldfrag(Ab, w * 32 +      (lane & 15), g0);
        short8 a1 = ldfrag(Ab, w * 32 + 16 + (lane & 15), g0);
        #pragma unroll
        for (int ct = 0; ct < 8; ++ct) {
            short8 bb = ldfrag(Bb, ct * 16 + (lane & 15), g0);
            acc[0][ct] = __builtin_amdgcn_mfma_f32_16x16x32_bf16(a0, bb, acc[0][ct], 0, 0, 0);
            acc[1][ct] = __builtin_amdgcn_mfma_f32_16x16x32_bf16(a1, bb, acc[1][ct], 0, 0, 0);
        }

        __builtin_amdgcn_sched_barrier(0);
        __builtin_amdgcn_s_barrier();          // done reading buf[kt&1]
        __builtin_amdgcn_sched_barrier(0);
    }

    // ---- epilogue: D lane map: col = lane&15, row = (lane>>4)*4 + r ----
    const int d  = lane & 15;
    const int rq = lane >> 4;
    #pragma unroll
    for (int rt = 0; rt < 2; ++rt) {
        #pragma unroll
        for (int ct = 0; ct < 8; ++ct) {
            const int m = mc * 8 + ct;
            #pragma unroll
            for (int r = 0; r < 4; ++r) {
                const int brow = w * 32 + rt * 16 + rq * 4 + r;
                const size_t idx = (((size_t)brow * M_ + m) * N_ + n) * D_ + d;
                hat[idx] = f2bf(acc[rt][ct][r]);
            }
        }
    }
}

// -----------------------------------------------------------------------------
// Kernel 2: dynamic routing (3 iterations), one block per batch element b.
// (unchanged from passing round-3 version)
// -----------------------------------------------------------------------------
__global__ __launch_bounds__(512) void routing(const unsigned short* __restrict__ hat,
                                               float* __restrict__ out) {
    __shared__ float blog[M_][N_];
    __shared__ float cmax[N_];
    __shared__ float rcsum[N_];

    const int b    = blockIdx.x;
    const int tid  = threadIdx.x;
    const int lane = tid & 63;
    const int w    = tid >> 6;

    #pragma unroll
    for (int m = 0; m < M_; ++m) blog[m][tid] = 0.f;
    __syncthreads();

    float ov[4][16];

    for (int it = 0; it < 3; ++it) {
        {
            float mx = -3.4e38f;
            #pragma unroll
            for (int m = 0; m < M_; ++m) mx = fmaxf(mx, blog[m][tid]);
            float s = 0.f;
            #pragma unroll
            for (int m = 0; m < M_; ++m) s += __expf(blog[m][tid] - mx);
            cmax[tid]  = mx;
            rcsum[tid] = 1.f / s;
        }
        __syncthreads();

        float sacc[4][16];
        #pragma unroll
        for (int q = 0; q < 4; ++q)
            #pragma unroll
            for (int dd = 0; dd < 16; ++dd) sacc[q][dd] = 0.f;

        for (int r = 0; r < 8; ++r) {
            const int nn = r * 64 + lane;
            #pragma unroll
            for (int q = 0; q < 4; ++q) {
                const int m = w * 4 + q;
                const float cm = __expf(blog[m][nn] - cmax[nn]) * rcsum[nn];
                const size_t base = (((size_t)b * M_ + m) * N_ + nn) * D_;
                short8 h0 = *(const short8*)(hat + base);
                short8 h1 = *(const short8*)(hat + base + 8);
                #pragma unroll
                for (int dd = 0; dd < 8; ++dd) {
                    sacc[q][dd]     += cm * bf2f((unsigned short)h0[dd]);
                    sacc[q][8 + dd] += cm * bf2f((unsigned short)h1[dd]);
                }
            }
        }
        #pragma unroll
        for (int off = 32; off >= 1; off >>= 1) {
            #pragma unroll
            for (int q = 0; q < 4; ++q)
                #pragma unroll
                for (int dd = 0; dd < 16; ++dd)
                    sacc[q][dd] += __shfl_xor(sacc[q][dd], off, 64);
        }
        #pragma unroll
        for (int q = 0; q < 4; ++q) {
            float s2 = 0.f;
            #pragma unroll
            for (int dd = 0; dd < 16; ++dd) s2 += sacc[q][dd] * sacc[q][dd];
            const float scale = s2 / (1.f + s2) / sqrtf(s2 + 1e-7f);
            #pragma unroll
            for (int dd = 0; dd < 16; ++dd) ov[q][dd] = scale * sacc[q][dd];
        }

        if (it < 2) {
            for (int r = 0; r < 8; ++r) {
                const int nn = r * 64 + lane;
                #pragma unroll
                for (int q = 0; q < 4; ++q) {
                    const int m = w * 4 + q;
                    const size_t base = (((size_t)b * M_ + m) * N_ + nn) * D_;
                    short8 h0 = *(const short8*)(hat + base);
                    short8 h1 = *(const short8*)(hat + base + 8);
                    float dot = 0.f;
                    #pragma unroll
                    for (int dd = 0; dd < 8; ++dd) {
                        dot += ov[q][dd]     * bf2f((unsigned short)h0[dd]);
                        dot += ov[q][8 + dd] * bf2f((unsigned short)h1[dd]);
                    }
                    blog[m][nn] += dot;
                }
            }
        }
        __syncthreads();
    }

    if (lane == 0) {
        #pragma unroll
        for (int q = 0; q < 4; ++q) {
            const int m = w * 4 + q;
            #pragma unroll
            for (int c4 = 0; c4 < 4; ++c4) {
                float4v v;
                v[0] = ov[q][c4 * 4 + 0];
                v[1] = ov[q][c4 * 4 + 1];
                v[2] = ov[q][c4 * 4 + 2];
                v[3] = ov[q][c4 * 4 + 3];
                *(float4v*)&out[((size_t)b * M_ + m) * D_ + c4 * 4] = v;
            }
        }
    }
}

extern "C" void kernel_launch(void* const* d_in, const int* in_sizes, int n_in,
                              void* d_out, int out_size, void* d_ws, size_t ws_size,
                              hipStream_t stream) {
    const float* x = (const float*)d_in[0];        // [128, 512, 256] fp32
    const float* W = (const float*)d_in[1];        // [32, 512, 16, 256] fp32
    unsigned short* hat = (unsigned short*)d_ws;   // bf16 [128,32,512,16] = 64 MB scratch
    float* out = (float*)d_out;                    // fp32 [128,32,16]

    dim3 g1(4, N_);
    hat_gemm<<<g1, dim3(256), 0, stream>>>(x, W, hat);
    routing<<<dim3(B_), dim3(512), 0, stream>>>(hat, out);
}